// Round 8
// baseline (297.741 us; speedup 1.0000x reference)
//
#include <hip/hip_runtime.h>

typedef unsigned short u16;
typedef __attribute__((ext_vector_type(8))) short bf16x8;    // 8 bf16 = 4 VGPR
typedef __attribute__((ext_vector_type(4))) float f32x4;
typedef __attribute__((ext_vector_type(16))) float f32x16;

#define BATCH 16
#define SEQ   2048
#define EMBD  512
#define NOUT  8
#define QB    64
#define KVB   64
#define NT    (SEQ/KVB)      // 32 KV tiles

#define GLOBAL_AS __attribute__((address_space(1)))
#define LDS_AS    __attribute__((address_space(3)))

__device__ __forceinline__ u16 f2bf(float f){          // f32 -> bf16 RNE
  unsigned u = __float_as_uint(f);
  u += 0x7fffu + ((u >> 16) & 1u);
  return (u16)(u >> 16);
}
__device__ __forceinline__ float b2f(short s){
  return __uint_as_float(((unsigned)(u16)s) << 16);
}

__device__ __forceinline__ void gload_lds16(const void* g, void* l){
  __builtin_amdgcn_global_load_lds((const GLOBAL_AS unsigned int*)g,
                                   (LDS_AS unsigned int*)l, 16, 0, 0);
}

// BarA: drains stage-DMA (vmcnt) + LDS; BarB: LDS only (no DMA in flight to
// wait on; keeps any global traffic moving). sched_barrier fences hoisting
// of register-only MFMAs past the waits (rule 18).
#define BAR_ALL()  do{ asm volatile("s_waitcnt vmcnt(0) lgkmcnt(0)" ::: "memory"); \
  __builtin_amdgcn_s_barrier(); __builtin_amdgcn_sched_barrier(0); }while(0)
#define BAR_LGKM() do{ asm volatile("s_waitcnt lgkmcnt(0)" ::: "memory");   \
  __builtin_amdgcn_s_barrier(); __builtin_amdgcn_sched_barrier(0); }while(0)

// ---------------------------------------------------------------------------
// Kernel 0: E[b*SEQ+n][e] = bf16(table[x[b,n]][e]); padding_idx==0 -> zeros.
// ---------------------------------------------------------------------------
__global__ __launch_bounds__(512) void k_embed(const int* __restrict__ x,
                                               const float* __restrict__ tab,
                                               u16* __restrict__ E){
  int r = blockIdx.x * 8 + (threadIdx.x >> 6);   // 0..32767
  int l = threadIdx.x & 63;
  int idx = x[r];
  float4 a = make_float4(0.f,0.f,0.f,0.f), c = a;
  if (idx != 0){
    const float4* src = (const float4*)(tab + (size_t)idx * EMBD);
    a = src[l*2]; c = src[l*2+1];
  }
  bf16x8 v;
  v[0]=f2bf(a.x); v[1]=f2bf(a.y); v[2]=f2bf(a.z); v[3]=f2bf(a.w);
  v[4]=f2bf(c.x); v[5]=f2bf(c.y); v[6]=f2bf(c.z); v[7]=f2bf(c.w);
  *(bf16x8*)(E + (size_t)r * EMBD + l*8) = v;
}

// ---------------------------------------------------------------------------
// Kernel 1: flash attention (Q=K=V=E) + per-Q-tile column max. KVB=64.
// R7 dataflow (32x32 e-split QKT, wave-private Vt, bf16 partial-S) with the
// loop re-pipelined to 2 barriers/tile:
//   phaseA(t): QKT(t) + [rescale+PV](t-1)  -> merged MFMA block
//   phaseB(t): stage K(t+1) + softmax(t) + V-transpose(t)
// PV deferred one tile; final PV after the loop.
// ---------------------------------------------------------------------------
__global__ __launch_bounds__(512, 2) void k_attn(const u16* __restrict__ E,
                                                 float* __restrict__ part){
  __shared__ u16   Klds[KVB * EMBD];     // 64 KB, 16B-chunk swizzled (c^row&7)
  __shared__ u16   Sb2[2][QB][72];       // 18 KB: partial S per e-half, bf16
  __shared__ u16   Ps[QB][72];           // 9.2 KB
  __shared__ u16   Vt[8 * 64 * 64];      // 64 KB: per-wave [64 e][64 tok] swz
  __shared__ float m_lds[QB], l_lds[QB], a_lds[QB];

  const int tid = threadIdx.x;
  const int w   = tid >> 6;              // wave 0..7
  const int l   = tid & 63;
  const int l15 = l & 15, lg = l >> 4;
  const int l31 = l & 31, hi = l >> 5;

  // XCD-affine decode: batch b's 32 q-tiles land on XCD (b&7).
  const int blk  = blockIdx.x;
  const int xcd  = blk & 7;
  const int slot = blk >> 3;             // 0..63
  const int b    = xcd + 8 * (slot >> 5);
  const int qt   = slot & 31;
  const size_t ebase = (size_t)b * SEQ * EMBD;

  // ---- QKT role decode + Q fragments (32 rows x 256 e -> 64 VGPR) ----
  const int iq2 = w & 1, jq2 = (w >> 1) & 1, eh = w >> 2;
  bf16x8 qf[16];
  {
    const u16* qp = E + ebase + (size_t)(qt*QB + iq2*32 + l31) * EMBD
                      + eh*256 + hi*8;
    #pragma unroll
    for (int ks = 0; ks < 16; ks++) qf[ks] = *(const bf16x8*)(qp + ks*16);
  }

  f32x4 acc[4][4];                       // O[ip*16+lg*4+rr][w*64+jp*16+l15]
  #pragma unroll
  for (int ip = 0; ip < 4; ip++)
    #pragma unroll
    for (int jp = 0; jp < 4; jp++) acc[ip][jp] = (f32x4){0.f,0.f,0.f,0.f};

  if (tid < QB){ m_lds[tid] = -INFINITY; l_lds[tid] = 0.f; }

  #define STAGE(tile_)                                                       \
    { const int kk0 = (tile_) * KVB;                                         \
      _Pragma("unroll")                                                      \
      for (int i = 0; i < 8; i++){                                           \
        const int r = w*8 + i;                                               \
        const u16* src = E + ebase + (size_t)(kk0 + r) * EMBD                \
                           + ((l ^ (r & 7)) * 8);                            \
        gload_lds16(src, Klds + (size_t)r * EMBD);                           \
      } }

  STAGE(0)

  const int quad = l & 15, c8h = l >> 4;

  for (int t = 0; t < NT; t++){
    const int k0 = t * KVB;
    BAR_ALL();                           // BarA: K(t) landed; Ps/Vt/alpha(t-1)

    // ---- phaseA: QK^T (32x32x16, e-half partial) ----
    f32x16 sacc = (f32x16){0.f,0.f,0.f,0.f,0.f,0.f,0.f,0.f,
                           0.f,0.f,0.f,0.f,0.f,0.f,0.f,0.f};
    {
      const int krow = jq2*32 + l31;     // K row (token) for B-frag
      const u16* kbase = &Klds[(size_t)krow * EMBD];
      const int r7 = krow & 7;
      __builtin_amdgcn_s_setprio(1);
      #pragma unroll
      for (int ks = 0; ks < 16; ks++){
        const int c = eh*32 + ks*2 + hi; // 16B chunk within 1KB K row
        bf16x8 kb = *(const bf16x8*)(kbase + ((c ^ r7) * 8));
        sacc = __builtin_amdgcn_mfma_f32_32x32x16_bf16(qf[ks], kb, sacc, 0,0,0);
      }
      __builtin_amdgcn_s_setprio(0);
    }

    // ---- phaseA: deferred rescale + PV(t-1) ----
    if (t > 0){
      {
        f32x4 al[4];
        int need = 0;
        #pragma unroll
        for (int ip = 0; ip < 4; ip++){
          al[ip] = *(f32x4*)&a_lds[ip*16 + lg*4];
          need |= (al[ip][0] != 1.f) | (al[ip][1] != 1.f) |
                  (al[ip][2] != 1.f) | (al[ip][3] != 1.f);
        }
        if (__any(need)){
          #pragma unroll
          for (int ip = 0; ip < 4; ip++)
            #pragma unroll
            for (int jp = 0; jp < 4; jp++)
              #pragma unroll
              for (int rr = 0; rr < 4; rr++) acc[ip][jp][rr] *= al[ip][rr];
        }
      }
      #pragma unroll
      for (int kt = 0; kt < 2; kt++){
        bf16x8 pa[4], vb[4];
        #pragma unroll
        for (int ip = 0; ip < 4; ip++)
          pa[ip] = *(const bf16x8*)&Ps[ip*16 + l15][kt*32 + lg*8];
        #pragma unroll
        for (int jp = 0; jp < 4; jp++){
          const int el = jp*16 + l15;                  // e_local
          const int ch = (kt*4 + lg) ^ (el & 7);
          vb[jp] = *(const bf16x8*)&Vt[(size_t)w*4096 + el*64 + ch*8];
        }
        __builtin_amdgcn_s_setprio(1);
        #pragma unroll
        for (int ip = 0; ip < 4; ip++)
          #pragma unroll
          for (int jp = 0; jp < 4; jp++)
            acc[ip][jp] = __builtin_amdgcn_mfma_f32_16x16x32_bf16(
                              pa[ip], vb[jp], acc[ip][jp], 0, 0, 0);
        __builtin_amdgcn_s_setprio(0);
      }
    }

    // ---- phaseA: issue V row loads for tile t (consumed in phaseB) ----
    bf16x8 vr[2][4];
    #pragma unroll
    for (int h = 0; h < 2; h++){
      const int c8 = c8h + h*4;          // e-chunk 0..7 in wave's 64-e slice
      const u16* vp = E + ebase + (size_t)(k0 + quad*4) * EMBD + w*64 + c8*8;
      vr[h][0] = *(const bf16x8*)(vp);
      vr[h][1] = *(const bf16x8*)(vp +   EMBD);
      vr[h][2] = *(const bf16x8*)(vp + 2*EMBD);
      vr[h][3] = *(const bf16x8*)(vp + 3*EMBD);
    }

    // ---- phaseA: write partial S (bf16) ----
    // C layout: col=l31 (token), row=(reg&3)+8*(reg>>2)+4*hi
    #pragma unroll
    for (int reg = 0; reg < 16; reg++){
      const int row = iq2*32 + (reg & 3) + 8*(reg >> 2) + 4*hi;
      Sb2[eh][row][jq2*32 + l31] = f2bf(sacc[reg]);
    }

    BAR_LGKM();                          // BarB: Sb2 ready; Klds reads done

    // ---- phaseB: stage K(t+1), covered by softmax+transpose ----
    if (t + 1 < NT) STAGE(t + 1)

    // ---- phaseB: online softmax (sums both e-halves) ----
    {
      const int row = tid >> 3, cg = tid & 7;
      bf16x8 a0 = *(const bf16x8*)&Sb2[0][row][cg*8];
      bf16x8 a1 = *(const bf16x8*)&Sb2[1][row][cg*8];
      float sv[8];
      #pragma unroll
      for (int i = 0; i < 8; i++) sv[i] = b2f(a0[i]) + b2f(a1[i]);
      float mx = fmaxf(fmaxf(fmaxf(sv[0],sv[1]), fmaxf(sv[2],sv[3])),
                       fmaxf(fmaxf(sv[4],sv[5]), fmaxf(sv[6],sv[7])));
      #pragma unroll
      for (int d = 1; d < 8; d <<= 1) mx = fmaxf(mx, __shfl_xor(mx, d));
      const float mold = m_lds[row], lold = l_lds[row];
      const float mnew = fmaxf(mold, mx);
      float pp[8];
      #pragma unroll
      for (int i = 0; i < 8; i++) pp[i] = __expf(sv[i] - mnew);
      float sum = ((pp[0]+pp[1])+(pp[2]+pp[3])) + ((pp[4]+pp[5])+(pp[6]+pp[7]));
      #pragma unroll
      for (int d = 1; d < 8; d <<= 1) sum += __shfl_xor(sum, d);
      const float alpha = __expf(mold - mnew);   // -inf -> 0 on first tile
      if (cg == 0){
        m_lds[row] = mnew;
        l_lds[row] = lold * alpha + sum;
        a_lds[row] = alpha;
      }
      bf16x8 pv;
      #pragma unroll
      for (int i = 0; i < 8; i++) pv[i] = (short)f2bf(pp[i]);
      *(bf16x8*)&Ps[row][cg*8] = pv;
    }

    // ---- phaseB: V transpose into wave-private Vt ----
    #pragma unroll
    for (int h = 0; h < 2; h++){
      const int c8 = c8h + h*4;
      #pragma unroll
      for (int i = 0; i < 8; i++){
        const int el = c8*8 + i;                       // e_local 0..63
        const int ch = (quad >> 1) ^ (el & 7);         // swizzled 16B chunk
        short4 sv; sv.x = vr[h][0][i]; sv.y = vr[h][1][i];
                   sv.z = vr[h][2][i]; sv.w = vr[h][3][i];
        *(short4*)&Vt[(size_t)w*4096 + el*64 + ch*8 + (quad&1)*4] = sv;
      }
    }
  }

  BAR_LGKM();                            // Ps/Vt/alpha(NT-1) visible

  // ---- final deferred rescale + PV(NT-1) ----
  {
    f32x4 al[4];
    int need = 0;
    #pragma unroll
    for (int ip = 0; ip < 4; ip++){
      al[ip] = *(f32x4*)&a_lds[ip*16 + lg*4];
      need |= (al[ip][0] != 1.f) | (al[ip][1] != 1.f) |
              (al[ip][2] != 1.f) | (al[ip][3] != 1.f);
    }
    if (__any(need)){
      #pragma unroll
      for (int ip = 0; ip < 4; ip++)
        #pragma unroll
        for (int jp = 0; jp < 4; jp++)
          #pragma unroll
          for (int rr = 0; rr < 4; rr++) acc[ip][jp][rr] *= al[ip][rr];
    }
  }
  #pragma unroll
  for (int kt = 0; kt < 2; kt++){
    bf16x8 pa[4], vb[4];
    #pragma unroll
    for (int ip = 0; ip < 4; ip++)
      pa[ip] = *(const bf16x8*)&Ps[ip*16 + l15][kt*32 + lg*8];
    #pragma unroll
    for (int jp = 0; jp < 4; jp++){
      const int el = jp*16 + l15;
      const int ch = (kt*4 + lg) ^ (el & 7);
      vb[jp] = *(const bf16x8*)&Vt[(size_t)w*4096 + el*64 + ch*8];
    }
    #pragma unroll
    for (int ip = 0; ip < 4; ip++)
      #pragma unroll
      for (int jp = 0; jp < 4; jp++)
        acc[ip][jp] = __builtin_amdgcn_mfma_f32_16x16x32_bf16(
                          pa[ip], vb[jp], acc[ip][jp], 0, 0, 0);
  }

  // ---- epilogue: 1/l scaling, column max over 64 q-rows, write partial ----
  #pragma unroll
  for (int ip = 0; ip < 4; ip++){
    f32x4 lv = *(f32x4*)&l_lds[ip*16 + lg*4];
    f32x4 inv;
    #pragma unroll
    for (int rr = 0; rr < 4; rr++) inv[rr] = 1.f / lv[rr];
    #pragma unroll
    for (int jp = 0; jp < 4; jp++)
      #pragma unroll
      for (int rr = 0; rr < 4; rr++) acc[ip][jp][rr] *= inv[rr];
  }
  #pragma unroll
  for (int jp = 0; jp < 4; jp++){
    float cm = -INFINITY;
    #pragma unroll
    for (int ip = 0; ip < 4; ip++)
      #pragma unroll
      for (int rr = 0; rr < 4; rr++) cm = fmaxf(cm, acc[ip][jp][rr]);
    cm = fmaxf(cm, __shfl_xor(cm, 16));
    cm = fmaxf(cm, __shfl_xor(cm, 32));
    if (lg == 0)
      part[(size_t)(b*32 + qt) * EMBD + w*64 + jp*16 + l15] = cm;
  }
}

// ---------------------------------------------------------------------------
// Kernel 2: pooled[b][e] = max over 32 q-tiles; out[b][o] = pooled.W[o] + b[o]
// ---------------------------------------------------------------------------
__global__ __launch_bounds__(512) void k_final(const float* __restrict__ part,
                                               const float* __restrict__ Wm,
                                               const float* __restrict__ bias,
                                               float* __restrict__ out){
  __shared__ float pooled[EMBD];
  const int b = blockIdx.x, tid = threadIdx.x;
  float mx = -INFINITY;
  const float* pb = part + (size_t)b * 32 * EMBD + tid;
  #pragma unroll
  for (int qt = 0; qt < 32; qt++) mx = fmaxf(mx, pb[qt * EMBD]);
  pooled[tid] = mx;
  __syncthreads();
  const int w = tid >> 6, l = tid & 63;     // w = output index (8 waves)
  float sum = 0.f;
  #pragma unroll
  for (int m = 0; m < 8; m++)
    sum += pooled[l + m*64] * Wm[w*EMBD + l + m*64];
  #pragma unroll
  for (int d = 1; d < 64; d <<= 1) sum += __shfl_xor(sum, d);
  if (l == 0) out[b * NOUT + w] = sum + bias[w];
}

// ---------------------------------------------------------------------------
extern "C" void kernel_launch(void* const* d_in, const int* in_sizes, int n_in,
                              void* d_out, int out_size, void* d_ws, size_t ws_size,
                              hipStream_t stream){
  const int*   x    = (const int*)  d_in[0];   // [16,2048]
  const float* tab  = (const float*)d_in[1];   // [32000,512]
  const float* Wm   = (const float*)d_in[2];   // [8,512]
  const float* bias = (const float*)d_in[3];   // [8]
  float* out = (float*)d_out;                  // [16,8]

  // ws: E bf16 [16*2048,512] = 32MB, then partials [16][32][512] f32 = 1MB
  u16*   E    = (u16*)d_ws;
  float* part = (float*)((char*)d_ws + (size_t)32 * 1024 * 1024);

  k_embed<<<BATCH*SEQ/8, 512, 0, stream>>>(x, tab, E);
  k_attn <<<BATCH*(SEQ/QB), 512, 0, stream>>>(E, part);
  k_final<<<BATCH, 512, 0, stream>>>(part, Wm, bias, out);
}